// Round 3
// baseline (84445.074 us; speedup 1.0000x reference)
//
#include <hip/hip_runtime.h>
#include <cstdint>
#include <cstddef>

// LSTM: T=512, B=64, E=1024, H=1024, fp32.
// Phase 1: Xproj[t][g][r][b] = bias_g[r] + sum_e Wx_g[r][e]*emb[t][b][e]  (big GEMM)
// Phase 2 (R3): per-step kernel, lanes=batch, weights consumed as wave-uniform
//   SGPR scalars (s_load), h as coalesced VMEM. R2 broadcast weights through the
//   LDS return bus (1 KB/instr) and was DS-bound at ~17 us/step; SMEM sidesteps
//   the broadcast entirely. Gate combine = last-arriver block via device-scope
//   atomic counter + threadfence (pre-activation scratch in ws).
// h_t stored directly in d_out (out[t] is the [H,B] slab). c state in ws tail.

#define TT 512
#define BB 64
#define EE 1024
#define HH 1024

// ---------------------------------------------------------------------------
// Phase 1: unchanged from R2 (~2.5 ms, VALU-bound fp32 GEMM).
// ---------------------------------------------------------------------------
__global__ __launch_bounds__(256)
void lstm_xproj_kernel(const float* __restrict__ emb,
                       const float* __restrict__ Wgx, const float* __restrict__ Wix,
                       const float* __restrict__ Wfx, const float* __restrict__ Wox,
                       const float* __restrict__ bg,  const float* __restrict__ bi,
                       const float* __restrict__ bfv, const float* __restrict__ bo,
                       float* __restrict__ xp, int row0)
{
    __shared__ float As[8][128];
    __shared__ float Bs[8][128];

    const int tid = threadIdx.x;
    const int m0 = blockIdx.x * 128;
    const int n0 = blockIdx.y * 128;
    const int gate = m0 >> 10;
    const int r0 = m0 & 1023;

    const float* __restrict__ W    = (gate == 0) ? Wgx : (gate == 1) ? Wix : (gate == 2) ? Wfx : Wox;
    const float* __restrict__ bias = (gate == 0) ? bg  : (gate == 1) ? bi  : (gate == 2) ? bfv : bo;

    const int li = tid >> 1;
    const int lq = (tid & 1) * 4;
    const int mi = (tid & 15) * 8;
    const int ni = (tid >> 4) * 8;

    const float* aptr = W   + (size_t)(r0 + li) * EE + lq;
    const float* bptr = emb + (size_t)(row0 + n0 + li) * EE + lq;

    float acc[8][8];
    #pragma unroll
    for (int p = 0; p < 8; ++p)
        #pragma unroll
        for (int q = 0; q < 8; ++q) acc[p][q] = 0.f;

    for (int k0 = 0; k0 < EE; k0 += 8) {
        float4 av = *(const float4*)(aptr + k0);
        float4 bv = *(const float4*)(bptr + k0);
        __syncthreads();
        As[lq + 0][li] = av.x; As[lq + 1][li] = av.y; As[lq + 2][li] = av.z; As[lq + 3][li] = av.w;
        Bs[lq + 0][li] = bv.x; Bs[lq + 1][li] = bv.y; Bs[lq + 2][li] = bv.z; Bs[lq + 3][li] = bv.w;
        __syncthreads();
        #pragma unroll
        for (int kk = 0; kk < 8; ++kk) {
            float a[8], b[8];
            *(float4*)&a[0] = *(const float4*)&As[kk][mi];
            *(float4*)&a[4] = *(const float4*)&As[kk][mi + 4];
            *(float4*)&b[0] = *(const float4*)&Bs[kk][ni];
            *(float4*)&b[4] = *(const float4*)&Bs[kk][ni + 4];
            #pragma unroll
            for (int p = 0; p < 8; ++p)
                #pragma unroll
                for (int q = 0; q < 8; ++q)
                    acc[p][q] += a[p] * b[q];
        }
    }

    #pragma unroll
    for (int p = 0; p < 8; ++p) {
        const int m = m0 + mi + p;
        const float bval = bias[r0 + mi + p];
        #pragma unroll
        for (int q0 = 0; q0 < 8; q0 += 4) {
            const int n = n0 + ni + q0;
            const int tloc = n >> 6;
            const int b = n & 63;
            float4 v = make_float4(acc[p][q0] + bval, acc[p][q0 + 1] + bval,
                                   acc[p][q0 + 2] + bval, acc[p][q0 + 3] + bval);
            *(float4*)&xp[((size_t)tloc * 4096 + m) * 64 + b] = v;
        }
    }
}

// ---------------------------------------------------------------------------
// Phase 2 step kernel (R3).
// Grid: 512 blocks x 512 threads. block = (g = bid&3, rgrp = bid>>2: 8 rows).
// Wave wv (0..7) = k-slice of 128. lane = batch b. acc[8] rows per lane.
// Weights: uniform float4 loads -> s_load; FMA reads weight from SGPR.
// Reduction over k-slices via 16 KB LDS; + xp; pre -> global scratch.
// Last of the 4 gate-blocks per rgrp (device-scope atomic counter) computes
// the nonlinearities and writes c (ws) and h_t (d_out).
// ---------------------------------------------------------------------------
__device__ __forceinline__ float sigmoid_f(float x) { return 1.f / (1.f + __expf(-x)); }
__device__ __forceinline__ float tanh_f(float x) {
    x = fminf(12.f, fmaxf(-12.f, x));
    float e = __expf(2.f * x);
    return (e - 1.f) / (e + 1.f);
}

__global__ __launch_bounds__(512)
void lstm_step_kernel(const float* __restrict__ Wgh, const float* __restrict__ Wih,
                      const float* __restrict__ Wfh, const float* __restrict__ Woh,
                      const float* __restrict__ xp,     // this step's [4][1024][64] slab
                      const float* __restrict__ hprev,  // out + (t-1)*H*B
                      float* __restrict__ hout,         // out + t*H*B
                      float* __restrict__ cstate,
                      float* __restrict__ pre,          // [4][1024][64] scratch
                      int* __restrict__ cnt,            // [128] arrival counters
                      int first)
{
    const int tid = threadIdx.x;
    const int lane = tid & 63;                 // batch b
    const int g = blockIdx.x & 3;
    const int rgrp = blockIdx.x >> 2;          // 0..127
    const int r0 = rgrp * 8;

    if (first) {
        // h=0, c=0: pre == xp. Only g==0 blocks combine; also zero counters.
        if (g != 0) return;
        const int r = r0 + (tid >> 6);
        const int b = lane;
        float pg = xp[(0 * 1024 + r) * 64 + b];
        float pi = xp[(1 * 1024 + r) * 64 + b];
        float pf = xp[(2 * 1024 + r) * 64 + b];
        float po = xp[(3 * 1024 + r) * 64 + b];
        float gg = tanh_f(pg), ii = sigmoid_f(pi), ff = sigmoid_f(pf), oo = sigmoid_f(po);
        (void)ff;
        float cn = gg * ii;                    // c_prev = 0
        cstate[r * 64 + b] = cn;
        hout[r * 64 + b] = tanh_f(cn) * oo;
        if (tid == 0) cnt[rgrp] = 0;
        return;
    }

    const int wv = __builtin_amdgcn_readfirstlane(tid >> 6);   // k-slice, wave-uniform
    const float* __restrict__ Wg = (g == 0) ? Wgh : (g == 1) ? Wih : (g == 2) ? Wfh : Woh;

    float acc[8] = {0.f, 0.f, 0.f, 0.f, 0.f, 0.f, 0.f, 0.f};
    {
        const float* __restrict__ hp = hprev + lane;
        const int kbeg = wv * 128;
        #pragma unroll 2
        for (int k = kbeg; k < kbeg + 128; k += 4) {
            float h0 = hp[(k + 0) * 64];
            float h1 = hp[(k + 1) * 64];
            float h2 = hp[(k + 2) * 64];
            float h3 = hp[(k + 3) * 64];
            #pragma unroll
            for (int j = 0; j < 8; ++j) {
                float4 w = *(const float4*)&Wg[(size_t)(r0 + j) * HH + k];  // uniform -> s_load
                acc[j] += w.x * h0 + w.y * h1 + w.z * h2 + w.w * h3;
            }
        }
    }

    // ---- reduce 8 k-slices via LDS; wave wv finalizes row r0+wv ----
    __shared__ float red[8][8][64];            // [kslice][row j][b]  = 16 KB
    #pragma unroll
    for (int j = 0; j < 8; ++j) red[wv][j][lane] = acc[j];
    __syncthreads();
    {
        const int r = r0 + wv;
        float s = red[0][wv][lane] + red[1][wv][lane] + red[2][wv][lane] + red[3][wv][lane]
                + red[4][wv][lane] + red[5][wv][lane] + red[6][wv][lane] + red[7][wv][lane];
        s += xp[((size_t)g * 1024 + r) * 64 + lane];
        pre[((size_t)g * 1024 + r) * 64 + lane] = s;
    }

    // ---- arrival protocol: last of 4 gate-blocks combines ----
    __shared__ int oldS;
    __threadfence();                           // release our pre stores (device scope)
    __syncthreads();
    if (tid == 0)
        oldS = __hip_atomic_fetch_add(&cnt[rgrp], 1, __ATOMIC_ACQ_REL, __HIP_MEMORY_SCOPE_AGENT);
    __syncthreads();
    if (oldS != 3) return;
    __threadfence();                           // acquire others' pre stores

    {
        const int r = r0 + (tid >> 6);
        const int b = lane;
        float pg = pre[(0 * 1024 + r) * 64 + b];
        float pi = pre[(1 * 1024 + r) * 64 + b];
        float pf = pre[(2 * 1024 + r) * 64 + b];
        float po = pre[(3 * 1024 + r) * 64 + b];
        float gg = tanh_f(pg), ii = sigmoid_f(pi), ff = sigmoid_f(pf), oo = sigmoid_f(po);
        float c  = cstate[r * 64 + b];
        float cn = gg * ii + c * ff;
        cstate[r * 64 + b] = cn;
        hout[r * 64 + b] = tanh_f(cn) * oo;
    }
    if (tid == 0) cnt[rgrp] = 0;               // re-arm for next step (next launch)
}

// ---------------------------------------------------------------------------
extern "C" void kernel_launch(void* const* d_in, const int* in_sizes, int n_in,
                              void* d_out, int out_size, void* d_ws, size_t ws_size,
                              hipStream_t stream)
{
    const float* emb = (const float*)d_in[0];
    const float* Wgx = (const float*)d_in[1];
    const float* Wgh = (const float*)d_in[2];
    const float* Wix = (const float*)d_in[3];
    const float* Wih = (const float*)d_in[4];
    const float* Wfx = (const float*)d_in[5];
    const float* Wfh = (const float*)d_in[6];
    const float* Wox = (const float*)d_in[7];
    const float* Woh = (const float*)d_in[8];
    const float* bg  = (const float*)d_in[9];
    const float* bi  = (const float*)d_in[10];
    const float* bfv = (const float*)d_in[11];
    const float* bo  = (const float*)d_in[12];
    float* out = (float*)d_out;
    char*  ws  = (char*)d_ws;

    const size_t per_t    = (size_t)4 * HH * BB * sizeof(float);   // 1 MiB per timestep
    const size_t cbytes   = (size_t)HH * BB * sizeof(float);       // 256 KiB c-state
    const size_t prebytes = (size_t)4 * HH * BB * sizeof(float);   // 1 MiB pre scratch
    const size_t tail     = cbytes + prebytes + 4096;              // + counters

    int Tc;
    if (ws_size >= per_t * TT + tail) {
        Tc = TT;
    } else {
        size_t avail = (ws_size > tail + 4096) ? (ws_size - tail - 4096) : 2 * per_t;
        Tc = (int)(avail / per_t);
        Tc &= ~1;
        if (Tc < 2) Tc = 2;
    }

    float* xp     = (float*)ws;
    float* cstate = (float*)(ws + (size_t)Tc * per_t);
    float* pre    = cstate + (size_t)HH * BB;
    int*   cnt    = (int*)(pre + (size_t)4 * HH * BB);

    for (int tc0 = 0; tc0 < TT; tc0 += Tc) {
        const int nt = (TT - tc0 < Tc) ? (TT - tc0) : Tc;
        dim3 g1(32, nt / 2);
        lstm_xproj_kernel<<<g1, 256, 0, stream>>>(emb, Wgx, Wix, Wfx, Wox,
                                                  bg, bi, bfv, bo, xp, tc0 * 64);
        for (int t = tc0; t < tc0 + nt; ++t) {
            const float* hprev = (t == 0) ? out : out + (size_t)(t - 1) * HH * BB;
            lstm_step_kernel<<<dim3(512), dim3(512), 0, stream>>>(
                Wgh, Wih, Wfh, Woh,
                xp + (size_t)(t - tc0) * 4 * HH * BB,
                hprev,
                out + (size_t)t * HH * BB,
                cstate, pre, cnt,
                (t == 0) ? 1 : 0);
        }
    }
}